// Round 8
// baseline (352.984 us; speedup 1.0000x reference)
//
#include <hip/hip_runtime.h>
#include <hip/hip_fp16.h>

#define N_NODES 100000
#define E_EDGES 1600000
#define F_IN    256
#define F_HID   64
#define F_OUT   16
#define NBKT    391           // buckets of 256 dst-nodes (99999>>8 = 390)
#define CAP     4608          // region size per bucket (mean 4092, +8 sigma)
#define PA_BLOCKS    391      // passA blocks, 4096 edges each
#define GEMM1_BLOCKS 782      // ceil(N/128)

typedef _Float16 half8   __attribute__((ext_vector_type(8)));
typedef float    floatx4 __attribute__((ext_vector_type(4)));

// ---------------------------------------------------------------------------
// K1 (fused): blocks [0,GEMM1_BLOCKS): support1 = x @ W1 via MFMA f16
// (W1 staged fp32->f16 directly into LDS in B-frag order — no prep pass).
// Blocks after: passA — bucket scatter into fixed CAP-sized regions
// (no prior histogram needed; cursor atomics count occupancy).
// ---------------------------------------------------------------------------
__global__ __launch_bounds__(256) void gemm1_passA_kernel(const float* __restrict__ x,
                                                          const float* __restrict__ W1,
                                                          _Float16* __restrict__ support1,
                                                          const int* __restrict__ esrc,
                                                          const int* __restrict__ edst,
                                                          const float* __restrict__ evals,
                                                          int* __restrict__ bucketCursor,
                                                          int2* __restrict__ tmp) {
    __shared__ __align__(16) char ldsbuf[32768];
    const int t = threadIdx.x;

    if (blockIdx.x >= GEMM1_BLOCKS) {
        // ---- passA: 4096 edges, 16 per thread (4 chunks of int4) ----
        int* hist = (int*)ldsbuf;          // NBKT ints (region-local counts)
        int* base = hist + NBKT;           // NBKT ints
        const int blk = blockIdx.x - GEMM1_BLOCKS;
        for (int i = t; i < NBKT; i += 256) hist[i] = 0;
        __syncthreads();
        const int base_e = blk * 4096;
        int rks[4][4];
#pragma unroll
        for (int ch = 0; ch < 4; ++ch) {
            const int e0 = base_e + ch * 1024 + t * 4;
            if (e0 < E_EDGES) {
                int4 d4 = *(const int4*)&edst[e0];
                rks[ch][0] = atomicAdd(&hist[d4.x >> 8], 1);
                rks[ch][1] = atomicAdd(&hist[d4.y >> 8], 1);
                rks[ch][2] = atomicAdd(&hist[d4.z >> 8], 1);
                rks[ch][3] = atomicAdd(&hist[d4.w >> 8], 1);
            }
        }
        __syncthreads();
        for (int i = t; i < NBKT; i += 256)
            base[i] = atomicAdd(&bucketCursor[i], hist[i]);
        __syncthreads();
#pragma unroll
        for (int ch = 0; ch < 4; ++ch) {
            const int e0 = base_e + ch * 1024 + t * 4;
            if (e0 < E_EDGES) {
                int4 d4 = *(const int4*)&edst[e0];    // L1-hot reload
                int4 s4 = *(const int4*)&esrc[e0];
                float4 v4 = *(const float4*)&evals[e0];
                const int dd[4] = {d4.x, d4.y, d4.z, d4.w};
                const int ss[4] = {s4.x, s4.y, s4.z, s4.w};
                const float vv[4] = {v4.x, v4.y, v4.z, v4.w};
#pragma unroll
                for (int u = 0; u < 4; ++u) {
                    const int bu = dd[u] >> 8;
                    const int bpos = base[bu] + rks[ch][u];
                    if (bpos < CAP)   // 8-sigma safety clamp, never hit
                        tmp[bu * CAP + bpos] =
                            make_int2(((dd[u] & 255) << 17) | ss[u],
                                      __float_as_int(vv[u]));
                }
            }
        }
        return;
    }

    // ---- MFMA gemm1: stage W1 fp32 -> f16 frag-order LDS ----
    _Float16* Bs = (_Float16*)ldsbuf;   // 32 KB
    for (int i = t; i < 16384; i += 256) {
        const int k = i >> 6, n = i & 63;
        const int kb = k >> 5, quad = (k >> 3) & 3, j = k & 7;
        const int nt = n >> 4, ln = n & 15;
        Bs[((kb * 4 + nt) * 64 + quad * 16 + ln) * 8 + j] = (_Float16)W1[i];
    }
    __syncthreads();

    const int wave = t >> 6;
    const int lane = t & 63;
    const int ln   = lane & 15;
    const int quad = lane >> 4;
    const int row0 = blockIdx.x * 128 + wave * 32;

    const float* xp[2];
#pragma unroll
    for (int mt = 0; mt < 2; ++mt) {
        int r = row0 + mt * 16 + ln;
        if (r > N_NODES - 1) r = N_NODES - 1;
        xp[mt] = x + (size_t)r * F_IN + quad * 8;
    }

    floatx4 acc[2][4] = {};

#pragma unroll 4
    for (int kb = 0; kb < 8; ++kb) {
        half8 a[2];
#pragma unroll
        for (int mt = 0; mt < 2; ++mt) {
            float4 v0 = *(const float4*)(xp[mt] + kb * 32);
            float4 v1 = *(const float4*)(xp[mt] + kb * 32 + 4);
            half8 h;
            h[0] = (_Float16)v0.x; h[1] = (_Float16)v0.y;
            h[2] = (_Float16)v0.z; h[3] = (_Float16)v0.w;
            h[4] = (_Float16)v1.x; h[5] = (_Float16)v1.y;
            h[6] = (_Float16)v1.z; h[7] = (_Float16)v1.w;
            a[mt] = h;
        }
#pragma unroll
        for (int nt = 0; nt < 4; ++nt) {
            half8 b = *(const half8*)&Bs[((size_t)((kb * 4 + nt) * 64 + lane)) * 8];
            acc[0][nt] = __builtin_amdgcn_mfma_f32_16x16x32_f16(a[0], b, acc[0][nt], 0, 0, 0);
            acc[1][nt] = __builtin_amdgcn_mfma_f32_16x16x32_f16(a[1], b, acc[1][nt], 0, 0, 0);
        }
    }

#pragma unroll
    for (int mt = 0; mt < 2; ++mt) {
        const int rbase = row0 + mt * 16 + quad * 4;
#pragma unroll
        for (int r = 0; r < 4; ++r) {
            const int row = rbase + r;
            if (row < N_NODES) {
#pragma unroll
                for (int nt = 0; nt < 4; ++nt)
                    support1[(size_t)row * F_HID + nt * 16 + ln] = (_Float16)acc[mt][nt][r];
            }
        }
    }
}

// ---------------------------------------------------------------------------
// Pass B: one block per 256-node bucket (391 blocks). LDS degree hist +
// scan + cursors; scatter within the L2-resident CAP region. Emits
// rowstart/deg; sorted_edges stays region-addressed (beg = b*CAP).
// ---------------------------------------------------------------------------
__global__ __launch_bounds__(256) void passB_kernel(const int2* __restrict__ tmp,
                                                    const int* __restrict__ bucketCursor,
                                                    int2* __restrict__ sorted_edges,
                                                    int* __restrict__ rowstart,
                                                    int* __restrict__ deg) {
    __shared__ int ldeg[256];
    __shared__ int lcur[256];
    __shared__ int s[256];
    const int t = threadIdx.x;
    const int b = blockIdx.x;
    const int beg = b * CAP;
    int cnt = bucketCursor[b];
    if (cnt > CAP) cnt = CAP;

    ldeg[t] = 0;
    __syncthreads();

    for (int p = t; p < cnt; p += 256) {
        int2 r = tmp[beg + p];
        atomicAdd(&ldeg[r.x >> 17], 1);
    }
    __syncthreads();

    const int v = ldeg[t];
    s[t] = v;
    __syncthreads();
#pragma unroll
    for (int off = 1; off < 256; off <<= 1) {
        const int y = (t >= off) ? s[t - off] : 0;
        __syncthreads();
        s[t] += y;
        __syncthreads();
    }
    const int run = s[t] - v;   // exclusive prefix
    lcur[t] = run;
    const int node = b * 256 + t;
    if (node < N_NODES) { rowstart[node] = beg + run; deg[node] = v; }
    __syncthreads();

    for (int p = t; p < cnt; p += 256) {
        int2 r = tmp[beg + p];
        const int pos = beg + atomicAdd(&lcur[r.x >> 17], 1);
        sorted_edges[pos] = make_int2(r.x & 0x1FFFF, r.y);
    }
}

// ---------------------------------------------------------------------------
// K2 fused: per dst node (one wave): h = relu(sum_e w*support1[src] + b1),
// support2[node] = h @ W2 (f16 out).
// Edges read DIRECTLY per lane (half-wave same-address -> L1 broadcast):
// no ds_bpermute in the hot loop, no register-preload prologue, no 64-cap.
// Lane (p = lane>>5, c = lane&31) handles edges 2k+p, dword = features 2c,2c+1.
// ---------------------------------------------------------------------------
__global__ __launch_bounds__(256) void spmm1_fused_kernel(const int* __restrict__ rowstart,
                                                          const int* __restrict__ deg,
                                                          const int2* __restrict__ sorted_edges,
                                                          const _Float16* __restrict__ support1,
                                                          const float* __restrict__ b1,
                                                          const float* __restrict__ W2,
                                                          _Float16* __restrict__ support2) {
    __shared__ float W2s[64 * 17];   // padded stride 17
    __shared__ float b1s[64];
    __shared__ float hs[4][64];
    const int t = threadIdx.x;
    for (int i = t; i < 1024; i += 256)
        W2s[(i >> 4) * 17 + (i & 15)] = W2[i];
    if (t < 64) b1s[t] = b1[t];
    __syncthreads();

    const int wave = t >> 6;
    const int lane = t & 63;
    const int node = blockIdx.x * 4 + wave;   // grid exact: 25000*4
    const int c = lane & 31;
    const int p = lane >> 5;

    const int beg = rowstart[node];
    const int cnt = deg[node];

    float acc0 = 0.f, acc1 = 0.f;
    const int pairs = (cnt + 1) >> 1;
    for (int k = 0; k < pairs; k += 8) {
        float w[8], f0[8], f1[8];
#pragma unroll
        for (int u = 0; u < 8; ++u) {
            const int idx = 2 * (k + u) + p;
            const int idc = (idx < cnt) ? idx : 0;       // clamped gather addr
            const int2 ev = sorted_edges[beg + idc];     // broadcast load
            w[u] = (idx < cnt) ? __int_as_float(ev.y) : 0.f;
            const unsigned d = *(const unsigned*)&support1[(size_t)ev.x * F_HID + 2 * c];
            const _Float16* hp = (const _Float16*)&d;
            f0[u] = (float)hp[0];
            f1[u] = (float)hp[1];
        }
#pragma unroll
        for (int u = 0; u < 8; ++u) {
            acc0 = fmaf(w[u], f0[u], acc0);
            acc1 = fmaf(w[u], f1[u], acc1);
        }
    }

    acc0 += __shfl_xor(acc0, 32);
    acc1 += __shfl_xor(acc1, 32);
    if (p == 0) {
        float2 hv;
        hv.x = fmaxf(acc0 + b1s[2 * c],     0.f);
        hv.y = fmaxf(acc1 + b1s[2 * c + 1], 0.f);
        *(float2*)&hs[wave][2 * c] = hv;
    }
    __syncthreads();

    // Epilogue h @ W2: quad covers a k-segment, reduce across quads.
    const int ln   = lane & 15;
    const int quad = lane >> 4;
    float o = 0.f;
#pragma unroll
    for (int kk = 0; kk < 16; ++kk) {
        const int k2 = quad * 16 + kk;
        o = fmaf(hs[wave][k2], W2s[k2 * 17 + ln], o);
    }
    o += __shfl_xor(o, 16);
    o += __shfl_xor(o, 32);
    if (quad == 0)
        support2[(size_t)node * F_OUT + ln] = (_Float16)o;
}

// ---------------------------------------------------------------------------
// K3 fused: per dst node (16 lanes): logits = sum_e w*support2[src] + b2,
// then log_softmax.  Direct broadcast edge loads; lane (p=j>>3, c=j&7)
// handles edges 2k+p, dword = features 2c,2c+1; combine via shfl_xor(8,16).
// ---------------------------------------------------------------------------
__global__ __launch_bounds__(256) void spmm2_fused_kernel(const int* __restrict__ rowstart,
                                                          const int* __restrict__ deg,
                                                          const int2* __restrict__ sorted_edges,
                                                          const _Float16* __restrict__ support2,
                                                          const float* __restrict__ b2,
                                                          float* __restrict__ out) {
    __shared__ float b2s[16];
    const int t = threadIdx.x;
    if (t < 16) b2s[t] = b2[t];
    __syncthreads();

    const int j    = t & 15;
    const int node = blockIdx.x * 16 + (t >> 4);   // grid exact: 6250*16
    const int c = j & 7;
    const int p = j >> 3;

    const int beg = rowstart[node];
    const int cnt = deg[node];

    float acc0 = 0.f, acc1 = 0.f;
    const int pairs = (cnt + 1) >> 1;
    for (int k = 0; k < pairs; k += 8) {
        float w[8], f0[8], f1[8];
#pragma unroll
        for (int u = 0; u < 8; ++u) {
            const int idx = 2 * (k + u) + p;
            const int idc = (idx < cnt) ? idx : 0;
            const int2 ev = sorted_edges[beg + idc];
            w[u] = (idx < cnt) ? __int_as_float(ev.y) : 0.f;
            const unsigned d = *(const unsigned*)&support2[(size_t)ev.x * F_OUT + 2 * c];
            const _Float16* hp = (const _Float16*)&d;
            f0[u] = (float)hp[0];
            f1[u] = (float)hp[1];
        }
#pragma unroll
        for (int u = 0; u < 8; ++u) {
            acc0 = fmaf(w[u], f0[u], acc0);
            acc1 = fmaf(w[u], f1[u], acc1);
        }
    }

    acc0 += __shfl_xor(acc0, 8, 16);
    acc1 += __shfl_xor(acc1, 8, 16);

    const float v0 = acc0 + b2s[2 * c];
    const float v1 = acc1 + b2s[2 * c + 1];
    float m = fmaxf(v0, v1);
#pragma unroll
    for (int off = 4; off > 0; off >>= 1)
        m = fmaxf(m, __shfl_xor(m, off, 16));
    float sum = __expf(v0 - m) + __expf(v1 - m);
#pragma unroll
    for (int off = 4; off > 0; off >>= 1)
        sum += __shfl_xor(sum, off, 16);
    if (p == 0) {
        const float lse = m + __logf(sum);
        float2 o = make_float2(v0 - lse, v1 - lse);
        *(float2*)&out[(size_t)node * F_OUT + 2 * c] = o;
    }
}

// ---------------------------------------------------------------------------
extern "C" void kernel_launch(void* const* d_in, const int* in_sizes, int n_in,
                              void* d_out, int out_size, void* d_ws, size_t ws_size,
                              hipStream_t stream) {
    const float* x     = (const float*)d_in[0];
    const int*   esrc  = (const int*)  d_in[1];
    const int*   edst  = (const int*)  d_in[2];
    const float* evals = (const float*)d_in[3];
    const float* W1    = (const float*)d_in[4];
    const float* b1    = (const float*)d_in[5];
    const float* W2    = (const float*)d_in[6];
    const float* b2    = (const float*)d_in[7];
    float* out = (float*)d_out;

    // Workspace layout (~45.6 MB); all segments 16 B-aligned.
    char* ws = (char*)d_ws;
    _Float16* support1     = (_Float16*)(ws);              // 12,800,000 B
    _Float16* support2     = (_Float16*)(ws + 12800000);   //  3,200,000 B
    int2*     tmp          = (int2*)    (ws + 16000000);   // 14,413,824 B (NBKT*CAP*8)
    int2*     sorted_edges = (int2*)    (ws + 30413824);   // 14,413,824 B
    int*      rowstart     = (int*)     (ws + 44827648);   //    400,000 B
    int*      deg          = (int*)     (ws + 45227648);   //    400,000 B
    int*      bucketCursor = (int*)     (ws + 45627648);   //      1,568 B

    hipMemsetAsync(bucketCursor, 0, NBKT * sizeof(int), stream);
    gemm1_passA_kernel<<<GEMM1_BLOCKS + PA_BLOCKS, 256, 0, stream>>>(
        x, W1, support1, esrc, edst, evals, bucketCursor, tmp);
    passB_kernel<<<NBKT, 256, 0, stream>>>(tmp, bucketCursor, sorted_edges, rowstart, deg);
    spmm1_fused_kernel<<<N_NODES / 4, 256, 0, stream>>>(rowstart, deg, sorted_edges,
                                                        support1, b1, W2, support2);
    spmm2_fused_kernel<<<N_NODES / 16, 256, 0, stream>>>(rowstart, deg, sorted_edges,
                                                         support2, b2, out);
}

// Round 9
// 293.588 us; speedup vs baseline: 1.2023x; 1.2023x over previous
//
#include <hip/hip_runtime.h>
#include <hip/hip_fp16.h>

#define N_NODES 100000
#define E_EDGES 1600000
#define F_IN    256
#define F_HID   64
#define F_OUT   16
#define NBKT    391           // buckets of 256 dst-nodes (99999>>8 = 390)
#define CAP     4608          // region size per bucket (mean 4092, +8 sigma)
#define PA_BLOCKS    391      // passA blocks, 4096 edges each
#define GEMM1_BLOCKS 782      // ceil(N/128)

typedef _Float16 half8   __attribute__((ext_vector_type(8)));
typedef float    floatx4 __attribute__((ext_vector_type(4)));

// ---------------------------------------------------------------------------
// K1 (fused): blocks [0,GEMM1_BLOCKS): support1 = x @ W1 via MFMA f16
// (W1 staged fp32->f16 directly into LDS in B-frag order).
// Blocks after: passA — bucket scatter into fixed CAP-sized regions.
// ---------------------------------------------------------------------------
__global__ __launch_bounds__(256) void gemm1_passA_kernel(const float* __restrict__ x,
                                                          const float* __restrict__ W1,
                                                          _Float16* __restrict__ support1,
                                                          const int* __restrict__ esrc,
                                                          const int* __restrict__ edst,
                                                          const float* __restrict__ evals,
                                                          int* __restrict__ bucketCursor,
                                                          int2* __restrict__ tmp) {
    __shared__ __align__(16) char ldsbuf[32768];
    const int t = threadIdx.x;

    if (blockIdx.x >= GEMM1_BLOCKS) {
        // ---- passA: 4096 edges, 16 per thread (4 chunks of int4) ----
        int* hist = (int*)ldsbuf;          // NBKT ints (region-local counts)
        int* base = hist + NBKT;           // NBKT ints
        const int blk = blockIdx.x - GEMM1_BLOCKS;
        for (int i = t; i < NBKT; i += 256) hist[i] = 0;
        __syncthreads();
        const int base_e = blk * 4096;
        int rks[4][4];
#pragma unroll
        for (int ch = 0; ch < 4; ++ch) {
            const int e0 = base_e + ch * 1024 + t * 4;
            if (e0 < E_EDGES) {
                int4 d4 = *(const int4*)&edst[e0];
                rks[ch][0] = atomicAdd(&hist[d4.x >> 8], 1);
                rks[ch][1] = atomicAdd(&hist[d4.y >> 8], 1);
                rks[ch][2] = atomicAdd(&hist[d4.z >> 8], 1);
                rks[ch][3] = atomicAdd(&hist[d4.w >> 8], 1);
            }
        }
        __syncthreads();
        for (int i = t; i < NBKT; i += 256)
            base[i] = atomicAdd(&bucketCursor[i], hist[i]);
        __syncthreads();
#pragma unroll
        for (int ch = 0; ch < 4; ++ch) {
            const int e0 = base_e + ch * 1024 + t * 4;
            if (e0 < E_EDGES) {
                int4 d4 = *(const int4*)&edst[e0];    // L1-hot reload
                int4 s4 = *(const int4*)&esrc[e0];
                float4 v4 = *(const float4*)&evals[e0];
                const int dd[4] = {d4.x, d4.y, d4.z, d4.w};
                const int ss[4] = {s4.x, s4.y, s4.z, s4.w};
                const float vv[4] = {v4.x, v4.y, v4.z, v4.w};
#pragma unroll
                for (int u = 0; u < 4; ++u) {
                    const int bu = dd[u] >> 8;
                    const int bpos = base[bu] + rks[ch][u];
                    if (bpos < CAP)   // 8-sigma safety clamp, never hit
                        tmp[bu * CAP + bpos] =
                            make_int2(((dd[u] & 255) << 17) | ss[u],
                                      __float_as_int(vv[u]));
                }
            }
        }
        return;
    }

    // ---- MFMA gemm1: stage W1 fp32 -> f16 frag-order LDS ----
    _Float16* Bs = (_Float16*)ldsbuf;   // 32 KB
    for (int i = t; i < 16384; i += 256) {
        const int k = i >> 6, n = i & 63;
        const int kb = k >> 5, quad = (k >> 3) & 3, j = k & 7;
        const int nt = n >> 4, ln = n & 15;
        Bs[((kb * 4 + nt) * 64 + quad * 16 + ln) * 8 + j] = (_Float16)W1[i];
    }
    __syncthreads();

    const int wave = t >> 6;
    const int lane = t & 63;
    const int ln   = lane & 15;
    const int quad = lane >> 4;
    const int row0 = blockIdx.x * 128 + wave * 32;

    const float* xp[2];
#pragma unroll
    for (int mt = 0; mt < 2; ++mt) {
        int r = row0 + mt * 16 + ln;
        if (r > N_NODES - 1) r = N_NODES - 1;
        xp[mt] = x + (size_t)r * F_IN + quad * 8;
    }

    floatx4 acc[2][4] = {};

#pragma unroll 4
    for (int kb = 0; kb < 8; ++kb) {
        half8 a[2];
#pragma unroll
        for (int mt = 0; mt < 2; ++mt) {
            float4 v0 = *(const float4*)(xp[mt] + kb * 32);
            float4 v1 = *(const float4*)(xp[mt] + kb * 32 + 4);
            half8 h;
            h[0] = (_Float16)v0.x; h[1] = (_Float16)v0.y;
            h[2] = (_Float16)v0.z; h[3] = (_Float16)v0.w;
            h[4] = (_Float16)v1.x; h[5] = (_Float16)v1.y;
            h[6] = (_Float16)v1.z; h[7] = (_Float16)v1.w;
            a[mt] = h;
        }
#pragma unroll
        for (int nt = 0; nt < 4; ++nt) {
            half8 b = *(const half8*)&Bs[((size_t)((kb * 4 + nt) * 64 + lane)) * 8];
            acc[0][nt] = __builtin_amdgcn_mfma_f32_16x16x32_f16(a[0], b, acc[0][nt], 0, 0, 0);
            acc[1][nt] = __builtin_amdgcn_mfma_f32_16x16x32_f16(a[1], b, acc[1][nt], 0, 0, 0);
        }
    }

#pragma unroll
    for (int mt = 0; mt < 2; ++mt) {
        const int rbase = row0 + mt * 16 + quad * 4;
#pragma unroll
        for (int r = 0; r < 4; ++r) {
            const int row = rbase + r;
            if (row < N_NODES) {
#pragma unroll
                for (int nt = 0; nt < 4; ++nt)
                    support1[(size_t)row * F_HID + nt * 16 + ln] = (_Float16)acc[mt][nt][r];
            }
        }
    }
}

// ---------------------------------------------------------------------------
// Pass B: one block per 256-node bucket (391 blocks). LDS degree hist +
// scan + cursors; scatter within the L2-resident CAP region.
// ---------------------------------------------------------------------------
__global__ __launch_bounds__(256) void passB_kernel(const int2* __restrict__ tmp,
                                                    const int* __restrict__ bucketCursor,
                                                    int2* __restrict__ sorted_edges,
                                                    int* __restrict__ rowstart,
                                                    int* __restrict__ deg) {
    __shared__ int ldeg[256];
    __shared__ int lcur[256];
    __shared__ int s[256];
    const int t = threadIdx.x;
    const int b = blockIdx.x;
    const int beg = b * CAP;
    int cnt = bucketCursor[b];
    if (cnt > CAP) cnt = CAP;

    ldeg[t] = 0;
    __syncthreads();

    for (int p = t; p < cnt; p += 256) {
        int2 r = tmp[beg + p];
        atomicAdd(&ldeg[r.x >> 17], 1);
    }
    __syncthreads();

    const int v = ldeg[t];
    s[t] = v;
    __syncthreads();
#pragma unroll
    for (int off = 1; off < 256; off <<= 1) {
        const int y = (t >= off) ? s[t - off] : 0;
        __syncthreads();
        s[t] += y;
        __syncthreads();
    }
    const int run = s[t] - v;   // exclusive prefix
    lcur[t] = run;
    const int node = b * 256 + t;
    if (node < N_NODES) { rowstart[node] = beg + run; deg[node] = v; }
    __syncthreads();

    for (int p = t; p < cnt; p += 256) {
        int2 r = tmp[beg + p];
        const int pos = beg + atomicAdd(&lcur[r.x >> 17], 1);
        sorted_edges[pos] = make_int2(r.x & 0x1FFFF, r.y);
    }
}

// ---------------------------------------------------------------------------
// K2 fused: per dst node (one wave): h = relu(sum_e w*support1[src] + b1),
// support2[node] = h @ W2 (f16 out).
// Preload edges into registers once, then QUAD-gather: lane (q = lane>>4
// edge-parity, c4 = lane&15 feature-quad) handles edges 4k+q via shfl
// broadcast, one uint2 (8 B, features 4c4..4c4+3) gather per edge.
// Reduce across parities via shfl_xor(16,32).
// ---------------------------------------------------------------------------
__global__ __launch_bounds__(256) void spmm1_fused_kernel(const int* __restrict__ rowstart,
                                                          const int* __restrict__ deg,
                                                          const int2* __restrict__ sorted_edges,
                                                          const _Float16* __restrict__ support1,
                                                          const float* __restrict__ b1,
                                                          const float* __restrict__ W2,
                                                          _Float16* __restrict__ support2) {
    __shared__ float W2s[64 * 17];   // padded stride 17
    __shared__ float b1s[64];
    __shared__ __align__(16) float hs[4][64];
    const int t = threadIdx.x;
    for (int i = t; i < 1024; i += 256)
        W2s[(i >> 4) * 17 + (i & 15)] = W2[i];
    if (t < 64) b1s[t] = b1[t];
    __syncthreads();

    const int wave = t >> 6;
    const int lane = t & 63;
    const int node = blockIdx.x * 4 + wave;   // grid exact: 25000*4
    const int c4 = lane & 15;                 // feature quad
    const int q  = lane >> 4;                 // edge parity 0..3

    const int beg = rowstart[node];
    const int cnt = deg[node];

    int   src_l = 0;
    float val_l = 0.f;
    if (lane < cnt) {
        int2 ev = sorted_edges[beg + lane];
        src_l = ev.x;
        val_l = __int_as_float(ev.y);
    }

    float acc0 = 0.f, acc1 = 0.f, acc2 = 0.f, acc3 = 0.f;
    const int kmax  = cnt < 64 ? cnt : 64;
    const int quads = (kmax + 3) >> 2;
    const int qp    = (quads + 3) & ~3;       // pad: w=0 slots are no-ops
    for (int k = 0; k < qp; k += 4) {
        float w[4]; uint2 d[4];
#pragma unroll
        for (int u = 0; u < 4; ++u) {
            const int idx = 4 * (k + u) + q;  // <= 63
            const int s2  = __shfl(src_l, idx);
            w[u] = __shfl(val_l, idx);
            d[u] = *(const uint2*)&support1[(size_t)s2 * F_HID + 4 * c4];
        }
#pragma unroll
        for (int u = 0; u < 4; ++u) {
            const _Float16* hp = (const _Float16*)&d[u];
            acc0 = fmaf(w[u], (float)hp[0], acc0);
            acc1 = fmaf(w[u], (float)hp[1], acc1);
            acc2 = fmaf(w[u], (float)hp[2], acc2);
            acc3 = fmaf(w[u], (float)hp[3], acc3);
        }
    }
    for (int k = 64 + q; k < cnt; k += 4) {   // rare tail, parity-split
        int2 ev = sorted_edges[beg + k];
        const float w = __int_as_float(ev.y);
        const uint2 d = *(const uint2*)&support1[(size_t)ev.x * F_HID + 4 * c4];
        const _Float16* hp = (const _Float16*)&d;
        acc0 = fmaf(w, (float)hp[0], acc0);
        acc1 = fmaf(w, (float)hp[1], acc1);
        acc2 = fmaf(w, (float)hp[2], acc2);
        acc3 = fmaf(w, (float)hp[3], acc3);
    }

    acc0 += __shfl_xor(acc0, 16); acc0 += __shfl_xor(acc0, 32);
    acc1 += __shfl_xor(acc1, 16); acc1 += __shfl_xor(acc1, 32);
    acc2 += __shfl_xor(acc2, 16); acc2 += __shfl_xor(acc2, 32);
    acc3 += __shfl_xor(acc3, 16); acc3 += __shfl_xor(acc3, 32);
    if (q == 0) {
        float4 hv;
        hv.x = fmaxf(acc0 + b1s[4 * c4],     0.f);
        hv.y = fmaxf(acc1 + b1s[4 * c4 + 1], 0.f);
        hv.z = fmaxf(acc2 + b1s[4 * c4 + 2], 0.f);
        hv.w = fmaxf(acc3 + b1s[4 * c4 + 3], 0.f);
        *(float4*)&hs[wave][4 * c4] = hv;
    }
    __syncthreads();

    // Epilogue h @ W2: quad covers a k-segment, reduce across quads.
    const int ln   = lane & 15;
    const int quad = lane >> 4;
    float o = 0.f;
#pragma unroll
    for (int kk = 0; kk < 16; ++kk) {
        const int k2 = quad * 16 + kk;
        o = fmaf(hs[wave][k2], W2s[k2 * 17 + ln], o);
    }
    o += __shfl_xor(o, 16);
    o += __shfl_xor(o, 32);
    if (quad == 0)
        support2[(size_t)node * F_OUT + ln] = (_Float16)o;
}

// ---------------------------------------------------------------------------
// K3 fused: per dst node (16 lanes): logits = sum_e w*support2[src] + b2,
// then log_softmax.  Preload + QUAD-gather at width 16: lane (p=j>>2,
// c=j&3) handles edges 4k+p, uint2 loads (features 4c..4c+3); combine via
// shfl_xor(4,8); softmax reduce over c via shfl_xor(1,2); float4 output.
// ---------------------------------------------------------------------------
__global__ __launch_bounds__(256) void spmm2_fused_kernel(const int* __restrict__ rowstart,
                                                          const int* __restrict__ deg,
                                                          const int2* __restrict__ sorted_edges,
                                                          const _Float16* __restrict__ support2,
                                                          const float* __restrict__ b2,
                                                          float* __restrict__ out) {
    __shared__ float b2s[16];
    const int t = threadIdx.x;
    if (t < 16) b2s[t] = b2[t];
    __syncthreads();

    const int j    = t & 15;
    const int node = blockIdx.x * 16 + (t >> 4);   // grid exact: 6250*16
    const int c = j & 3;
    const int p = j >> 2;

    const int beg = rowstart[node];
    const int cnt = deg[node];

    int   src_a = 0, src_b = 0;
    float val_a = 0.f, val_b = 0.f;
    if (j < cnt)      { int2 ev = sorted_edges[beg + j];      src_a = ev.x; val_a = __int_as_float(ev.y); }
    if (j + 16 < cnt) { int2 ev = sorted_edges[beg + 16 + j]; src_b = ev.x; val_b = __int_as_float(ev.y); }

    float acc0 = 0.f, acc1 = 0.f, acc2 = 0.f, acc3 = 0.f;
    {   // batch 1: edges 0..15 (4 quad-iters; w=0 beyond cnt)
        float w[4]; uint2 d[4];
#pragma unroll
        for (int u = 0; u < 4; ++u) {
            const int idx = 4 * u + p;
            const int s2  = __shfl(src_a, idx, 16);
            w[u] = __shfl(val_a, idx, 16);
            d[u] = *(const uint2*)&support2[(size_t)s2 * F_OUT + 4 * c];
        }
#pragma unroll
        for (int u = 0; u < 4; ++u) {
            const _Float16* hp = (const _Float16*)&d[u];
            acc0 = fmaf(w[u], (float)hp[0], acc0);
            acc1 = fmaf(w[u], (float)hp[1], acc1);
            acc2 = fmaf(w[u], (float)hp[2], acc2);
            acc3 = fmaf(w[u], (float)hp[3], acc3);
        }
    }
    if (cnt > 16) {   // batch 2: edges 16..31
        float w[4]; uint2 d[4];
#pragma unroll
        for (int u = 0; u < 4; ++u) {
            const int idx = 4 * u + p;
            const int s2  = __shfl(src_b, idx, 16);
            w[u] = __shfl(val_b, idx, 16);
            d[u] = *(const uint2*)&support2[(size_t)s2 * F_OUT + 4 * c];
        }
#pragma unroll
        for (int u = 0; u < 4; ++u) {
            const _Float16* hp = (const _Float16*)&d[u];
            acc0 = fmaf(w[u], (float)hp[0], acc0);
            acc1 = fmaf(w[u], (float)hp[1], acc1);
            acc2 = fmaf(w[u], (float)hp[2], acc2);
            acc3 = fmaf(w[u], (float)hp[3], acc3);
        }
    }
    for (int k = 32 + p; k < cnt; k += 4) {   // rare tail, parity-split
        int2 ev = sorted_edges[beg + k];
        const float w = __int_as_float(ev.y);
        const uint2 d = *(const uint2*)&support2[(size_t)ev.x * F_OUT + 4 * c];
        const _Float16* hp = (const _Float16*)&d;
        acc0 = fmaf(w, (float)hp[0], acc0);
        acc1 = fmaf(w, (float)hp[1], acc1);
        acc2 = fmaf(w, (float)hp[2], acc2);
        acc3 = fmaf(w, (float)hp[3], acc3);
    }

    acc0 += __shfl_xor(acc0, 4, 16); acc0 += __shfl_xor(acc0, 8, 16);
    acc1 += __shfl_xor(acc1, 4, 16); acc1 += __shfl_xor(acc1, 8, 16);
    acc2 += __shfl_xor(acc2, 4, 16); acc2 += __shfl_xor(acc2, 8, 16);
    acc3 += __shfl_xor(acc3, 4, 16); acc3 += __shfl_xor(acc3, 8, 16);

    const float v0 = acc0 + b2s[4 * c];
    const float v1 = acc1 + b2s[4 * c + 1];
    const float v2 = acc2 + b2s[4 * c + 2];
    const float v3 = acc3 + b2s[4 * c + 3];
    float m = fmaxf(fmaxf(v0, v1), fmaxf(v2, v3));
    m = fmaxf(m, __shfl_xor(m, 1, 16));
    m = fmaxf(m, __shfl_xor(m, 2, 16));
    float sum = __expf(v0 - m) + __expf(v1 - m) + __expf(v2 - m) + __expf(v3 - m);
    sum += __shfl_xor(sum, 1, 16);
    sum += __shfl_xor(sum, 2, 16);
    if (p == 0) {
        const float lse = m + __logf(sum);
        float4 o = make_float4(v0 - lse, v1 - lse, v2 - lse, v3 - lse);
        *(float4*)&out[(size_t)node * F_OUT + 4 * c] = o;
    }
}

// ---------------------------------------------------------------------------
extern "C" void kernel_launch(void* const* d_in, const int* in_sizes, int n_in,
                              void* d_out, int out_size, void* d_ws, size_t ws_size,
                              hipStream_t stream) {
    const float* x     = (const float*)d_in[0];
    const int*   esrc  = (const int*)  d_in[1];
    const int*   edst  = (const int*)  d_in[2];
    const float* evals = (const float*)d_in[3];
    const float* W1    = (const float*)d_in[4];
    const float* b1    = (const float*)d_in[5];
    const float* W2    = (const float*)d_in[6];
    const float* b2    = (const float*)d_in[7];
    float* out = (float*)d_out;

    // Workspace layout (~45.6 MB); all segments 16 B-aligned.
    char* ws = (char*)d_ws;
    _Float16* support1     = (_Float16*)(ws);              // 12,800,000 B
    _Float16* support2     = (_Float16*)(ws + 12800000);   //  3,200,000 B
    int2*     tmp          = (int2*)    (ws + 16000000);   // 14,413,824 B (NBKT*CAP*8)
    int2*     sorted_edges = (int2*)    (ws + 30413824);   // 14,413,824 B
    int*      rowstart     = (int*)     (ws + 44827648);   //    400,000 B
    int*      deg          = (int*)     (ws + 45227648);   //    400,000 B
    int*      bucketCursor = (int*)     (ws + 45627648);   //      1,568 B

    hipMemsetAsync(bucketCursor, 0, NBKT * sizeof(int), stream);
    gemm1_passA_kernel<<<GEMM1_BLOCKS + PA_BLOCKS, 256, 0, stream>>>(
        x, W1, support1, esrc, edst, evals, bucketCursor, tmp);
    passB_kernel<<<NBKT, 256, 0, stream>>>(tmp, bucketCursor, sorted_edges, rowstart, deg);
    spmm1_fused_kernel<<<N_NODES / 4, 256, 0, stream>>>(rowstart, deg, sorted_edges,
                                                        support1, b1, W2, support2);
    spmm2_fused_kernel<<<N_NODES / 16, 256, 0, stream>>>(rowstart, deg, sorted_edges,
                                                         support2, b2, out);
}